// Round 5
// baseline (302.941 us; speedup 1.0000x reference)
//
#include <hip/hip_runtime.h>

// EPCOR eval path on MI355X. Shapes fixed per reference setup.
// pd-free formulation: the 128x128 MFMA tile is recomputed in 3 passes
// (A: softmax stats, B: cross sums, C: corr) — identical tile_core ensures
// bit-identical pd values across passes, so argmax/threshold tests agree.
#define BB 8
#define CC 64
#define NN 2048
#define MM 2048
#define KSEL 613            // 0-based index of the 614-th smallest (int(2048*0.3)=614)

// Output layout (floats): src_corr [B,3,N] | src_weight [B,N] | mask_src [B,N] | mask_tgt [B,M]
#define OUT_W  (BB * 3 * NN)          // 49152
#define OUT_MS (OUT_W + BB * NN)      // 65536
#define OUT_MT (OUT_MS + BB * NN)     // 81920

typedef __bf16 bf16x8 __attribute__((ext_vector_type(8)));
typedef float f32x4 __attribute__((ext_vector_type(4)));
typedef unsigned short u16;

#define MFMA16 __builtin_amdgcn_mfma_f32_16x16x32_bf16

// 3-level RTNE bf16 split: a ~= a0 + a1 + a2 (residual ~2^-27 rel)
__device__ __forceinline__ void split3(float a, u16& u0, u16& u1, u16& u2) {
    __bf16 h0 = (__bf16)a; float f0 = (float)h0;
    float r1 = a - f0;
    __bf16 h1 = (__bf16)r1; float f1 = (float)h1;
    float r2 = r1 - f1;
    __bf16 h2 = (__bf16)r2;
    u0 = __builtin_bit_cast(u16, h0);
    u1 = __builtin_bit_cast(u16, h1);
    u2 = __builtin_bit_cast(u16, h2);
}

// ---------- K0: transpose [B,C,N]->[B,N,C], 3-level bf16 split, fused sqnorm ----------
__global__ __launch_bounds__(256) void split_k(const float* __restrict__ E,
                                               float* __restrict__ sq,
                                               unsigned* __restrict__ T0,
                                               unsigned* __restrict__ T1,
                                               unsigned* __restrict__ T2) {
    __shared__ float Ls[64][65];
    __shared__ float sacc[64];
    int b = blockIdx.y, n0 = blockIdx.x * 64, t = threadIdx.x;
    const float* Eb = E + (size_t)b * CC * NN + n0;
#pragma unroll
    for (int i = 0; i < 4; ++i) {
        int idx = (i << 8) + t, c = idx >> 4, nq = idx & 15;
        float4 v = *(const float4*)(Eb + (size_t)c * NN + (nq << 2));
        Ls[c][nq * 4 + 0] = v.x; Ls[c][nq * 4 + 1] = v.y;
        Ls[c][nq * 4 + 2] = v.z; Ls[c][nq * 4 + 3] = v.w;
    }
    __syncthreads();
    int j = t & 31, nn = t >> 5;
#pragma unroll
    for (int p = 0; p < 8; ++p) {
        int n = (p << 3) + nn;
        float a = Ls[2 * j][n], c = Ls[2 * j + 1][n];
        float s = a * a + c * c;
#pragma unroll
        for (int d = 1; d < 32; d <<= 1) s += __shfl_xor(s, d);
        if (j == 0) sacc[n] = s;
        u16 a0, a1, a2, c0, c1, c2;
        split3(a, a0, a1, a2);
        split3(c, c0, c1, c2);
        size_t row = (size_t)(b * NN + n0 + n) * 32 + j;
        T0[row] = (unsigned)a0 | ((unsigned)c0 << 16);
        T1[row] = (unsigned)a1 | ((unsigned)c1 << 16);
        T2[row] = (unsigned)a2 | ((unsigned)c2 << 16);
    }
    __syncthreads();
    if (t < 64) sq[b * NN + n0 + t] = sacc[t];
}

#define LD8(P) (*(const bf16x8*)(const void*)(P))

// Shared MFMA tile core: 128x128, bf16x6 terms (00,01,10,11 then 02,20), K=64 as 2 chunks.
// MUST stay identical across passes A/B/C for bit-identical results.
__device__ __forceinline__ void tile_core(
    const char* pA0, const char* pA1, const char* pA2,
    const char* pB0, const char* pB1, const char* pB2,
    f32x4 (&acc)[4][4]) {
#pragma unroll
    for (int kc = 0; kc < 2; ++kc) {
        int ko = kc << 6;              // 64B per K=32 chunk
        bf16x8 a0[4], b0[4], ax[4], bx[4];
#pragma unroll
        for (int i = 0; i < 4; ++i) {
            a0[i] = LD8(pA0 + ko + i * 2048);
            b0[i] = LD8(pB0 + ko + i * 2048);
            ax[i] = LD8(pA1 + ko + i * 2048);
            bx[i] = LD8(pB1 + ko + i * 2048);
        }
#pragma unroll
        for (int mg = 0; mg < 4; ++mg)
#pragma unroll
            for (int ng = 0; ng < 4; ++ng)
                acc[ng][mg] = MFMA16(a0[ng], b0[mg], acc[ng][mg], 0, 0, 0);
#pragma unroll
        for (int mg = 0; mg < 4; ++mg)
#pragma unroll
            for (int ng = 0; ng < 4; ++ng)
                acc[ng][mg] = MFMA16(a0[ng], bx[mg], acc[ng][mg], 0, 0, 0);
#pragma unroll
        for (int mg = 0; mg < 4; ++mg)
#pragma unroll
            for (int ng = 0; ng < 4; ++ng)
                acc[ng][mg] = MFMA16(ax[ng], b0[mg], acc[ng][mg], 0, 0, 0);
#pragma unroll
        for (int mg = 0; mg < 4; ++mg)
#pragma unroll
            for (int ng = 0; ng < 4; ++ng)
                acc[ng][mg] = MFMA16(ax[ng], bx[mg], acc[ng][mg], 0, 0, 0);
#pragma unroll
        for (int i = 0; i < 4; ++i) {
            ax[i] = LD8(pA2 + ko + i * 2048);
            bx[i] = LD8(pB2 + ko + i * 2048);
        }
#pragma unroll
        for (int mg = 0; mg < 4; ++mg)
#pragma unroll
            for (int ng = 0; ng < 4; ++ng)
                acc[ng][mg] = MFMA16(a0[ng], bx[mg], acc[ng][mg], 0, 0, 0);
#pragma unroll
        for (int mg = 0; mg < 4; ++mg)
#pragma unroll
            for (int ng = 0; ng < 4; ++ng)
                acc[ng][mg] = MFMA16(ax[ng], b0[mg], acc[ng][mg], 0, 0, 0);
    }
}

// Common prologue: XCD-aware remap (b = flat%8), tile core, o = 2*acc - xx - yy in place.
// C/D layout: col(m) = lane&15=q (m = mbase+mg*16+q), row(n) = (lane>>4)*4+r (n = nbase+ng*16+g*4+r).
#define TILE_PROLOGUE                                                                  \
    int flat = blockIdx.x + (blockIdx.y << 4) + (blockIdx.z << 8);                     \
    int b = flat & 7, rest = flat >> 3;                                                \
    int mt = rest & 15, nt = rest >> 4;                                                \
    int n0 = nt << 7, m0 = mt << 7;                                                    \
    int t = threadIdx.x, lane = t & 63, w = t >> 6;                                    \
    int wn = w >> 1, wm = w & 1;                                                       \
    int g = lane >> 4, q = lane & 15;                                                  \
    size_t offA = ((size_t)(b * NN + n0 + wn * 64 + q) << 7) + (g << 4);               \
    size_t offB = ((size_t)(b * MM + m0 + wm * 64 + q) << 7) + (g << 4);               \
    f32x4 acc[4][4] = {};                                                              \
    tile_core((const char*)A0 + offA, (const char*)A1 + offA, (const char*)A2 + offA,  \
              (const char*)B0 + offB, (const char*)B1 + offB, (const char*)B2 + offB,  \
              acc);                                                                    \
    int nbase = n0 + wn * 64;                                                          \
    int mbase = m0 + wm * 64;                                                          \
    {                                                                                  \
        float xv_[4][4], yv_[4];                                                       \
        _Pragma("unroll") for (int ng = 0; ng < 4; ++ng)                               \
            _Pragma("unroll") for (int r = 0; r < 4; ++r)                              \
                xv_[ng][r] = xx[b * NN + nbase + ng * 16 + g * 4 + r];                 \
        _Pragma("unroll") for (int mg = 0; mg < 4; ++mg)                               \
            yv_[mg] = yy[b * MM + mbase + mg * 16 + q];                                \
        _Pragma("unroll") for (int ng = 0; ng < 4; ++ng)                               \
            _Pragma("unroll") for (int r = 0; r < 4; ++r)                              \
                _Pragma("unroll") for (int mg = 0; mg < 4; ++mg)                       \
                    acc[ng][mg][r] = 2.f * acc[ng][mg][r] - xv_[ng][r] - yv_[mg];      \
    }

// ---------- Pass A: row/col softmax stat partials ----------
__global__ __launch_bounds__(256, 4) void gemmA_k(
    const unsigned* __restrict__ A0, const unsigned* __restrict__ A1, const unsigned* __restrict__ A2,
    const unsigned* __restrict__ B0, const unsigned* __restrict__ B1, const unsigned* __restrict__ B2,
    const float* __restrict__ xx, const float* __restrict__ yy,
    float* __restrict__ rpM, float* __restrict__ rpS,
    float* __restrict__ cpM, float* __restrict__ cpS) {
    __shared__ float rowm2[2][128], rows2[2][128];
    __shared__ float colm2[2][128], cols2[2][128];
    TILE_PROLOGUE

    // row partials (max/sum over this wave's 64 m): fold mg in-register, shfl over q
#pragma unroll
    for (int ng = 0; ng < 4; ++ng)
#pragma unroll
        for (int r = 0; r < 4; ++r) {
            float mx = fmaxf(fmaxf(acc[ng][0][r], acc[ng][1][r]),
                             fmaxf(acc[ng][2][r], acc[ng][3][r]));
#pragma unroll
            for (int d = 1; d < 16; d <<= 1) mx = fmaxf(mx, __shfl_xor(mx, d));
            float s = __expf(acc[ng][0][r] - mx) + __expf(acc[ng][1][r] - mx) +
                      __expf(acc[ng][2][r] - mx) + __expf(acc[ng][3][r] - mx);
#pragma unroll
            for (int d = 1; d < 16; d <<= 1) s += __shfl_xor(s, d);
            if (q == 0) {
                int nl = wn * 64 + ng * 16 + g * 4 + r;
                rowm2[wm][nl] = mx;
                rows2[wm][nl] = s;
            }
        }

    // col partials (max/sum over this wave's 64 n): fold ng,r in-register, shfl over g
#pragma unroll
    for (int mg = 0; mg < 4; ++mg) {
        float cx = -3.4e38f;
#pragma unroll
        for (int ng = 0; ng < 4; ++ng)
#pragma unroll
            for (int r = 0; r < 4; ++r) cx = fmaxf(cx, acc[ng][mg][r]);
        cx = fmaxf(cx, __shfl_xor(cx, 16));
        cx = fmaxf(cx, __shfl_xor(cx, 32));
        float cs = 0.f;
#pragma unroll
        for (int ng = 0; ng < 4; ++ng)
#pragma unroll
            for (int r = 0; r < 4; ++r) cs += __expf(acc[ng][mg][r] - cx);
        cs += __shfl_xor(cs, 16);
        cs += __shfl_xor(cs, 32);
        if (lane < 16) {
            int ml = wm * 64 + mg * 16 + q;
            colm2[wn][ml] = cx;
            cols2[wn][ml] = cs;
        }
    }
    __syncthreads();

    if (t < 128) {
        float ma = rowm2[0][t], mb = rowm2[1][t];
        float M = fmaxf(ma, mb);
        float S = rows2[0][t] * __expf(ma - M) + rows2[1][t] * __expf(mb - M);
        size_t base = ((size_t)(b * 16 + mt)) * NN + n0 + t;
        rpM[base] = M;
        rpS[base] = S;
    } else {
        int m = t - 128;
        float ma = colm2[0][m], mb = colm2[1][m];
        float M = fmaxf(ma, mb);
        float S = cols2[0][m] * __expf(ma - M) + cols2[1][m] * __expf(mb - M);
        size_t base = ((size_t)(b * 16 + nt)) * MM + m0 + m;
        cpM[base] = M;
        cpS[base] = S;
    }
}

// ---------- Pass B: cross sums (sRow = sum_m colsoftmax, sCol = sum_n rowsoftmax) ----------
__global__ __launch_bounds__(256, 4) void gemmB_k(
    const unsigned* __restrict__ A0, const unsigned* __restrict__ A1, const unsigned* __restrict__ A2,
    const unsigned* __restrict__ B0, const unsigned* __restrict__ B1, const unsigned* __restrict__ B2,
    const float* __restrict__ xx, const float* __restrict__ yy,
    const float* __restrict__ rowmax, const float* __restrict__ rowsum,
    const float* __restrict__ colmax, const float* __restrict__ colsum,
    float* __restrict__ sRowp,   // [B,16,N]
    float* __restrict__ sColp) { // [B,16,M]
    __shared__ float rowS[2][128], colS[2][128];
    TILE_PROLOGUE

    float rmv[4][4], riv[4][4];
#pragma unroll
    for (int ng = 0; ng < 4; ++ng)
#pragma unroll
        for (int r = 0; r < 4; ++r) {
            int n = nbase + ng * 16 + g * 4 + r;
            rmv[ng][r] = rowmax[b * NN + n];
            riv[ng][r] = 1.f / rowsum[b * NN + n];
        }
    float cmv[4], civ[4];
#pragma unroll
    for (int mg = 0; mg < 4; ++mg) {
        int m = mbase + mg * 16 + q;
        cmv[mg] = colmax[b * MM + m];
        civ[mg] = 1.f / colsum[b * MM + m];
    }

    // sCol partial: per column m, sum over the wave's 64 n of exp(o-rowmax[n])/rowsum[n]
#pragma unroll
    for (int mg = 0; mg < 4; ++mg) {
        float scp = 0.f;
#pragma unroll
        for (int ng = 0; ng < 4; ++ng)
#pragma unroll
            for (int r = 0; r < 4; ++r)
                scp += __expf(acc[ng][mg][r] - rmv[ng][r]) * riv[ng][r];
        scp += __shfl_xor(scp, 16);
        scp += __shfl_xor(scp, 32);
        if (lane < 16) colS[wn][wm * 64 + mg * 16 + q] = scp;
    }

    // sRow partial: per row n, sum over the wave's 64 m of exp(o-colmax[m])/colsum[m]
#pragma unroll
    for (int ng = 0; ng < 4; ++ng)
#pragma unroll
        for (int r = 0; r < 4; ++r) {
            float srp = __expf(acc[ng][0][r] - cmv[0]) * civ[0] +
                        __expf(acc[ng][1][r] - cmv[1]) * civ[1] +
                        __expf(acc[ng][2][r] - cmv[2]) * civ[2] +
                        __expf(acc[ng][3][r] - cmv[3]) * civ[3];
#pragma unroll
            for (int d = 1; d < 16; d <<= 1) srp += __shfl_xor(srp, d);
            if (q == 0) rowS[wm][wn * 64 + ng * 16 + g * 4 + r] = srp;
        }
    __syncthreads();

    if (t < 128) {
        sRowp[((size_t)(b * 16 + mt)) * NN + n0 + t] = rowS[0][t] + rowS[1][t];
    } else {
        int m = t - 128;
        sColp[((size_t)(b * 16 + nt)) * MM + m0 + m] = colS[0][m] + colS[1][m];
    }
}

// ---------- Pass C: masked corr partials (cs,d0,d1,d2 per row) ----------
__global__ __launch_bounds__(256, 3) void gemmC_k(
    const unsigned* __restrict__ A0, const unsigned* __restrict__ A1, const unsigned* __restrict__ A2,
    const unsigned* __restrict__ B0, const unsigned* __restrict__ B1, const unsigned* __restrict__ B2,
    const float* __restrict__ xx, const float* __restrict__ yy,
    const float* __restrict__ rowmax, const float* __restrict__ rowsum,
    const float* __restrict__ sRow, const float* __restrict__ sCol,
    const float* __restrict__ rth, const float* __restrict__ cth,
    const float* __restrict__ tgt,
    float* __restrict__ corrP) {  // [B,16,4,N]
    __shared__ float cred[2][128][4];
    TILE_PROLOGUE

    float cthv = cth[b], rthv = rth[b];
    float tg0[4], tg1[4], tg2[4];
    bool mtg[4];
#pragma unroll
    for (int mg = 0; mg < 4; ++mg) {
        int m = mbase + mg * 16 + q;
        const float* tb = tgt + (size_t)b * 3 * MM + m;
        tg0[mg] = tb[0]; tg1[mg] = tb[MM]; tg2[mg] = tb[2 * MM];
        mtg[mg] = sCol[b * MM + m] < cthv;
    }

#pragma unroll
    for (int ng = 0; ng < 4; ++ng)
#pragma unroll
        for (int r = 0; r < 4; ++r) {
            int n = nbase + ng * 16 + g * 4 + r;
            float rm = rowmax[b * NN + n];
            float ri = 1.f / rowsum[b * NN + n];
            bool msrc = sRow[b * NN + n] < rthv;
            float cs = 0.f, d0 = 0.f, d1 = 0.f, d2 = 0.f;
#pragma unroll
            for (int mg = 0; mg < 4; ++mg) {
                float o = acc[ng][mg][r];
                bool keep = msrc || mtg[mg] || (o == rm);
                if (keep) {
                    float s = __expf(o - rm) * ri;
                    cs += s;
                    d0 += s * tg0[mg];
                    d1 += s * tg1[mg];
                    d2 += s * tg2[mg];
                }
            }
#pragma unroll
            for (int d = 1; d < 16; d <<= 1) {
                cs += __shfl_xor(cs, d);
                d0 += __shfl_xor(d0, d);
                d1 += __shfl_xor(d1, d);
                d2 += __shfl_xor(d2, d);
            }
            if (q == 0) {
                int nl = wn * 64 + ng * 16 + g * 4 + r;
                cred[wm][nl][0] = cs; cred[wm][nl][1] = d0;
                cred[wm][nl][2] = d1; cred[wm][nl][3] = d2;
            }
        }
    __syncthreads();

    if (t < 128) {
        size_t base = ((size_t)(b * 16 + mt) * 4) * NN + n0 + t;
        corrP[base]          = cred[0][t][0] + cred[1][t][0];
        corrP[base + NN]     = cred[0][t][1] + cred[1][t][1];
        corrP[base + 2 * NN] = cred[0][t][2] + cred[1][t][2];
        corrP[base + 3 * NN] = cred[0][t][3] + cred[1][t][3];
    }
}

// ---------- combine row/col stat partials (online softmax merge). z=0 rows, z=1 cols ----------
__global__ __launch_bounds__(256) void comb_rc_k(const float* __restrict__ rpM,
                                                 const float* __restrict__ rpS,
                                                 const float* __restrict__ cpM,
                                                 const float* __restrict__ cpS,
                                                 float* __restrict__ rowmax,
                                                 float* __restrict__ rowsum,
                                                 float* __restrict__ colmax,
                                                 float* __restrict__ colsum) {
    int b = blockIdx.y, which = blockIdx.z;
    int i = blockIdx.x * 256 + threadIdx.x;
    const float* pM = which ? cpM : rpM;
    const float* pS = which ? cpS : rpS;
    float* oM = which ? colmax : rowmax;
    float* oS = which ? colsum : rowsum;
    float Mv = -3.4e38f;
#pragma unroll
    for (int k = 0; k < 16; ++k) Mv = fmaxf(Mv, pM[(size_t)(b * 16 + k) * 2048 + i]);
    float S = 0.f;
#pragma unroll
    for (int k = 0; k < 16; ++k) {
        size_t o = (size_t)(b * 16 + k) * 2048 + i;
        S += pS[o] * __expf(pM[o] - Mv);
    }
    oM[b * 2048 + i] = Mv;
    oS[b * 2048 + i] = S;
}

// ---------- combine cross partials. z=0: sRow, z=1: sCol (16 slices each) ----------
__global__ __launch_bounds__(256) void comb_s_k(const float* __restrict__ sRowp,
                                                const float* __restrict__ sColp,
                                                float* __restrict__ sRow,
                                                float* __restrict__ sCol) {
    int b = blockIdx.y, which = blockIdx.z;
    int i = blockIdx.x * 256 + threadIdx.x;
    if (!which) {
        float s = 0.f;
#pragma unroll
        for (int k = 0; k < 16; ++k) s += sRowp[(size_t)(b * 16 + k) * NN + i];
        sRow[b * NN + i] = s;
    } else {
        float s = 0.f;
#pragma unroll
        for (int k = 0; k < 16; ++k) s += sColp[(size_t)(b * 16 + k) * MM + i];
        sCol[b * MM + i] = s;
    }
}

// ---------- combine corr partials, final normalize ----------
__global__ __launch_bounds__(256) void comb_corr_k(const float* __restrict__ corrP,
                                                   float* __restrict__ out) {
    int b = blockIdx.y;
    int i = blockIdx.x * 256 + threadIdx.x;
    float cs = 0.f, d0 = 0.f, d1 = 0.f, d2 = 0.f;
#pragma unroll
    for (int k = 0; k < 16; ++k) {
        size_t base = ((size_t)(b * 16 + k) * 4) * NN + i;
        cs += corrP[base];
        d0 += corrP[base + NN];
        d1 += corrP[base + 2 * NN];
        d2 += corrP[base + 3 * NN];
    }
    cs = (cs < 1e-5f) ? 1e-5f : cs;
    out[(b * 3 + 0) * NN + i] = d0 / cs;
    out[(b * 3 + 1) * NN + i] = d1 / cs;
    out[(b * 3 + 2) * NN + i] = d2 / cs;
}

// ---------- 614-th smallest via binary search on float bits (values >= 0) ----------
__global__ __launch_bounds__(64) void select_k(const float* __restrict__ sRow,
                                               const float* __restrict__ sCol,
                                               float* __restrict__ rth,
                                               float* __restrict__ cth) {
    int kind = blockIdx.x, b = blockIdx.y, t = threadIdx.x;
    const float* vals = (kind == 0) ? (sRow + b * NN) : (sCol + b * MM);
    float v[32];
#pragma unroll
    for (int i = 0; i < 32; ++i) v[i] = vals[t + (i << 6)];
    unsigned lo = 0u, hi = 0x7F800000u;
    while (lo < hi) {
        unsigned mid = lo + ((hi - lo) >> 1);
        float pv = __uint_as_float(mid);
        int c = 0;
#pragma unroll
        for (int i = 0; i < 32; ++i) c += (v[i] <= pv) ? 1 : 0;
#pragma unroll
        for (int off = 32; off > 0; off >>= 1) c += __shfl_down(c, off);
        c = __shfl(c, 0);
        if (c >= KSEL + 1) hi = mid; else lo = mid + 1;
    }
    if (t == 0) { if (kind == 0) rth[b] = __uint_as_float(lo); else cth[b] = __uint_as_float(lo); }
}

// ---------- masks + src_weight ----------
__global__ __launch_bounds__(256) void masks_k(const float* __restrict__ sRow,
                                               const float* __restrict__ sCol,
                                               const float* __restrict__ rth,
                                               const float* __restrict__ cth,
                                               float* __restrict__ out) {
    int b = blockIdx.x, t = threadIdx.x;
    float r = rth[b], c = cth[b];
    int cnt = 0;
    bool ms[8];
#pragma unroll
    for (int i = 0; i < 8; ++i) {
        int n = t + (i << 8);
        ms[i] = sRow[b * NN + n] < r;
        out[OUT_MS + b * NN + n] = ms[i] ? 1.f : 0.f;
        out[OUT_MT + b * MM + n] = (sCol[b * MM + n] < c) ? 1.f : 0.f;
        cnt += ms[i] ? 0 : 1;
    }
#pragma unroll
    for (int off = 32; off > 0; off >>= 1) cnt += __shfl_down(cnt, off);
    __shared__ int wcnt[4];
    int wave = t >> 6, lane = t & 63;
    if (lane == 0) wcnt[wave] = cnt;
    __syncthreads();
    float inv = 1.f / (float)(wcnt[0] + wcnt[1] + wcnt[2] + wcnt[3]);
#pragma unroll
    for (int i = 0; i < 8; ++i) {
        int n = t + (i << 8);
        out[OUT_W + b * NN + n] = ms[i] ? 0.f : inv;
    }
}

extern "C" void kernel_launch(void* const* d_in, const int* in_sizes, int n_in,
                              void* d_out, int out_size, void* d_ws, size_t ws_size,
                              hipStream_t stream) {
    const float* src_emb = (const float*)d_in[0];   // [B,C,N]
    const float* tgt_emb = (const float*)d_in[1];   // [B,C,M]
    // d_in[2] = src, unused by the reference
    const float* tgt = (const float*)d_in[3];       // [B,3,M]
    float* out = (float*)d_out;

    float* ws = (float*)d_ws;
    float* xx     = ws;                               // B*N
    float* yy     = xx + BB * NN;                     // B*M
    float* rowmax = yy + BB * MM;                     // B*N
    float* rowsum = rowmax + BB * NN;                 // B*N
    float* colmax = rowsum + BB * NN;                 // B*M
    float* colsum = colmax + BB * MM;                 // B*M
    float* sRow   = colsum + BB * MM;                 // B*N
    float* sCol   = sRow + BB * NN;                   // B*M
    float* rth    = sCol + BB * MM;                   // B
    float* cth    = rth + BB;                         // B
    float* rpM    = cth + BB;                         // B*16*N
    float* rpS    = rpM + (size_t)BB * 16 * NN;       // B*16*N
    float* cpM    = rpS + (size_t)BB * 16 * NN;       // B*16*M
    float* cpS    = cpM + (size_t)BB * 16 * MM;       // B*16*M
    float* sRowp  = cpS + (size_t)BB * 16 * MM;       // B*16*N
    float* sColp  = sRowp + (size_t)BB * 16 * NN;     // B*16*M
    float* corrP  = sColp + (size_t)BB * 16 * MM;     // B*16*4*N
    unsigned* At0 = (unsigned*)(corrP + (size_t)BB * 16 * 4 * NN);  // each B*N*32 u32
    unsigned* At1 = At0 + (size_t)BB * NN * 32;
    unsigned* At2 = At1 + (size_t)BB * NN * 32;
    unsigned* Bt0 = At2 + (size_t)BB * NN * 32;
    unsigned* Bt1 = Bt0 + (size_t)BB * MM * 32;
    unsigned* Bt2 = Bt1 + (size_t)BB * MM * 32;

    dim3 gemm_grid(16, 16, BB);

    split_k<<<dim3(NN / 64, BB), 256, 0, stream>>>(src_emb, xx, At0, At1, At2);
    split_k<<<dim3(MM / 64, BB), 256, 0, stream>>>(tgt_emb, yy, Bt0, Bt1, Bt2);
    gemmA_k<<<gemm_grid, 256, 0, stream>>>(At0, At1, At2, Bt0, Bt1, Bt2,
                                           xx, yy, rpM, rpS, cpM, cpS);
    comb_rc_k<<<dim3(2048 / 256, BB, 2), 256, 0, stream>>>(rpM, rpS, cpM, cpS,
                                                           rowmax, rowsum, colmax, colsum);
    gemmB_k<<<gemm_grid, 256, 0, stream>>>(At0, At1, At2, Bt0, Bt1, Bt2,
                                           xx, yy, rowmax, rowsum, colmax, colsum,
                                           sRowp, sColp);
    comb_s_k<<<dim3(2048 / 256, BB, 2), 256, 0, stream>>>(sRowp, sColp, sRow, sCol);
    select_k<<<dim3(2, BB), 64, 0, stream>>>(sRow, sCol, rth, cth);
    masks_k<<<dim3(BB), 256, 0, stream>>>(sRow, sCol, rth, cth, out);
    gemmC_k<<<gemm_grid, 256, 0, stream>>>(At0, At1, At2, Bt0, Bt1, Bt2,
                                           xx, yy, rowmax, rowsum, sRow, sCol,
                                           rth, cth, tgt, corrP);
    comb_corr_k<<<dim3(2048 / 256, BB), 256, 0, stream>>>(corrP, out);
}

// Round 6
// 195.930 us; speedup vs baseline: 1.5462x; 1.5462x over previous
//
#include <hip/hip_runtime.h>

// EPCOR eval path on MI355X. Shapes fixed per reference setup.
#define BB 8
#define CC 64
#define NN 2048
#define MM 2048
#define KSEL 613            // 0-based index of the 614-th smallest (int(2048*0.3)=614)
#define MT 32               // m tiles of 64 (cross pass)
#define MT2 16              // m tiles of 128 (gemm partials)
#define NT2 16              // n tiles of 128 (gemm partials)
#define NCH 16              // n chunks of 128 (cross pass)

// Output layout (floats): src_corr [B,3,N] | src_weight [B,N] | mask_src [B,N] | mask_tgt [B,M]
#define OUT_W  (BB * 3 * NN)          // 49152
#define OUT_MS (OUT_W + BB * NN)      // 65536
#define OUT_MT (OUT_MS + BB * NN)     // 81920

typedef __bf16 bf16x8 __attribute__((ext_vector_type(8)));
typedef float f32x4 __attribute__((ext_vector_type(4)));
typedef unsigned short u16;

#define MFMA16 __builtin_amdgcn_mfma_f32_16x16x32_bf16

// 3-level RTNE bf16 split: a ~= a0 + a1 + a2 (residual ~2^-27 rel)
__device__ __forceinline__ void split3(float a, u16& u0, u16& u1, u16& u2) {
    __bf16 h0 = (__bf16)a; float f0 = (float)h0;
    float r1 = a - f0;
    __bf16 h1 = (__bf16)r1; float f1 = (float)h1;
    float r2 = r1 - f1;
    __bf16 h2 = (__bf16)r2;
    u0 = __builtin_bit_cast(u16, h0);
    u1 = __builtin_bit_cast(u16, h1);
    u2 = __builtin_bit_cast(u16, h2);
}

// ---------- K0: transpose [B,C,N]->[B,N,C], 3-level bf16 split, fused sqnorm ----------
// grid (NN/64, BB), block 256. Outputs T0/T1/T2 as u32 arrays [B][N][32] (2 bf16 per u32).
__global__ __launch_bounds__(256) void split_k(const float* __restrict__ E,
                                               float* __restrict__ sq,
                                               unsigned* __restrict__ T0,
                                               unsigned* __restrict__ T1,
                                               unsigned* __restrict__ T2) {
    __shared__ float Ls[64][65];
    __shared__ float sacc[64];
    int b = blockIdx.y, n0 = blockIdx.x * 64, t = threadIdx.x;
    const float* Eb = E + (size_t)b * CC * NN + n0;
#pragma unroll
    for (int i = 0; i < 4; ++i) {
        int idx = (i << 8) + t, c = idx >> 4, nq = idx & 15;
        float4 v = *(const float4*)(Eb + (size_t)c * NN + (nq << 2));
        Ls[c][nq * 4 + 0] = v.x; Ls[c][nq * 4 + 1] = v.y;
        Ls[c][nq * 4 + 2] = v.z; Ls[c][nq * 4 + 3] = v.w;
    }
    __syncthreads();
    int j = t & 31, nn = t >> 5;
#pragma unroll
    for (int p = 0; p < 8; ++p) {
        int n = (p << 3) + nn;
        float a = Ls[2 * j][n], c = Ls[2 * j + 1][n];
        float s = a * a + c * c;
#pragma unroll
        for (int d = 1; d < 32; d <<= 1) s += __shfl_xor(s, d);
        if (j == 0) sacc[n] = s;
        u16 a0, a1, a2, c0, c1, c2;
        split3(a, a0, a1, a2);
        split3(c, c0, c1, c2);
        size_t row = (size_t)(b * NN + n0 + n) * 32 + j;
        T0[row] = (unsigned)a0 | ((unsigned)c0 << 16);
        T1[row] = (unsigned)a1 | ((unsigned)c1 << 16);
        T2[row] = (unsigned)a2 | ((unsigned)c2 << 16);
    }
    __syncthreads();
    if (t < 64) sq[b * NN + n0 + t] = sacc[t];
}

// Stage one [128 rows][32 k] bf16 tile (8KB) from [B,N,64] bf16 global into linear LDS,
// with the bank-conflict swizzle applied on the GLOBAL source. Swizzle uses (row>>1)&3:
// even/odd rows occupy disjoint 64B halves of the 128B bank space; (row>>1)&3 spreads
// 4 consecutive even (and odd) rows across the 4 16B slots -> residual 2-way (free).
__device__ __forceinline__ void stage_tile(u16* dst, const unsigned* src,
                                           int base_nm, int kc, int t) {
#pragma unroll
    for (int i = 0; i < 2; ++i) {
        int d = (((i << 8) + t) << 4);          // byte offset in tile
        int nn_ = d >> 6, c4 = (d >> 4) & 3;
        const char* gs = (const char*)src + ((size_t)(base_nm + nn_) << 7) +
                         ((size_t)kc << 6) + ((c4 ^ ((nn_ >> 1) & 3)) << 4);
        __builtin_amdgcn_global_load_lds(
            (const __attribute__((address_space(1))) void*)gs,
            (__attribute__((address_space(3))) void*)((char*)dst + d), 16, 0, 0);
    }
}

// Read one MFMA operand fragment (8 bf16, 16B) with the matching read-side swizzle.
__device__ __forceinline__ bf16x8 frag(const u16* tile, int nloc, int g) {
    return *(const bf16x8*)((const char*)tile + (nloc << 6) + ((g ^ ((nloc >> 1) & 3)) << 4));
}

// ---------- K1: pd = 2*A^T B - xx - yy via pre-split bf16x6 MFMA; fused softmax partials ----------
// 128x128 tile, 4 waves (2x2 of 64x64). Per kc (K=32): phase1 {a0,b0,a1,b1} -> 00,01,10,11;
// phase2 restage {a2,b2} -> 02,20. XCD remap: b = flat%8 keeps each batch's split arrays
// on one XCD's L2. Accumulation order identical to the verified round-3 kernel.
__global__ __launch_bounds__(256, 3) void gemm_pd_k(
    const unsigned* __restrict__ A0, const unsigned* __restrict__ A1, const unsigned* __restrict__ A2,
    const unsigned* __restrict__ B0, const unsigned* __restrict__ B1, const unsigned* __restrict__ B2,
    const float* __restrict__ xx, const float* __restrict__ yy,
    float* __restrict__ pd,
    float* __restrict__ rpM, float* __restrict__ rpS,
    float* __restrict__ cpM, float* __restrict__ cpS) {
    __shared__ u16 Ta0[128 * 32], Tb0[128 * 32], Tax[128 * 32], Tbx[128 * 32];
    __shared__ float rowm2[2][128], rows2[2][128];
    __shared__ float colm2[2][128], cols2[2][128];
    int flat = blockIdx.x + (blockIdx.y << 4) + (blockIdx.z << 8);  // grid (16,16,8)
    int b = flat & 7, rest = flat >> 3;
    int mt = rest & 15, nt = rest >> 4;
    int n0 = nt << 7;
    int m0 = mt << 7;
    int t = threadIdx.x, lane = t & 63, w = t >> 6;
    int wn = w >> 1, wm = w & 1;       // 2x2 wave grid: wave owns 64n x 64m
    int g = lane >> 4, q = lane & 15;
    int baseA = b * NN + n0, baseB = b * MM + m0;

    f32x4 acc[4][4] = {};              // [ng][mg]

#pragma unroll
    for (int kc = 0; kc < 2; ++kc) {
        stage_tile(Ta0, A0, baseA, kc, t);
        stage_tile(Tb0, B0, baseB, kc, t);
        stage_tile(Tax, A1, baseA, kc, t);
        stage_tile(Tbx, B1, baseB, kc, t);
        __syncthreads();
        bf16x8 fa0[4], fb0[4], fax[4], fbx[4];
#pragma unroll
        for (int i = 0; i < 4; ++i) {
            fa0[i] = frag(Ta0, wn * 64 + i * 16 + q, g);
            fb0[i] = frag(Tb0, wm * 64 + i * 16 + q, g);
            fax[i] = frag(Tax, wn * 64 + i * 16 + q, g);
            fbx[i] = frag(Tbx, wm * 64 + i * 16 + q, g);
        }
#pragma unroll
        for (int mg = 0; mg < 4; ++mg)
#pragma unroll
            for (int ng = 0; ng < 4; ++ng)
                acc[ng][mg] = MFMA16(fa0[ng], fb0[mg], acc[ng][mg], 0, 0, 0);
#pragma unroll
        for (int mg = 0; mg < 4; ++mg)
#pragma unroll
            for (int ng = 0; ng < 4; ++ng)
                acc[ng][mg] = MFMA16(fa0[ng], fbx[mg], acc[ng][mg], 0, 0, 0);
#pragma unroll
        for (int mg = 0; mg < 4; ++mg)
#pragma unroll
            for (int ng = 0; ng < 4; ++ng)
                acc[ng][mg] = MFMA16(fax[ng], fb0[mg], acc[ng][mg], 0, 0, 0);
#pragma unroll
        for (int mg = 0; mg < 4; ++mg)
#pragma unroll
            for (int ng = 0; ng < 4; ++ng)
                acc[ng][mg] = MFMA16(fax[ng], fbx[mg], acc[ng][mg], 0, 0, 0);
        __syncthreads();
        stage_tile(Tax, A2, baseA, kc, t);
        stage_tile(Tbx, B2, baseB, kc, t);
        __syncthreads();
#pragma unroll
        for (int i = 0; i < 4; ++i) {
            fax[i] = frag(Tax, wn * 64 + i * 16 + q, g);
            fbx[i] = frag(Tbx, wm * 64 + i * 16 + q, g);
        }
#pragma unroll
        for (int mg = 0; mg < 4; ++mg)
#pragma unroll
            for (int ng = 0; ng < 4; ++ng)
                acc[ng][mg] = MFMA16(fa0[ng], fbx[mg], acc[ng][mg], 0, 0, 0);
#pragma unroll
        for (int mg = 0; mg < 4; ++mg)
#pragma unroll
            for (int ng = 0; ng < 4; ++ng)
                acc[ng][mg] = MFMA16(fax[ng], fb0[mg], acc[ng][mg], 0, 0, 0);
        __syncthreads();
    }

    // ---- epilogue: C/D layout is col = lane&15 (m), row = (lane>>4)*4 + reg (n) ----
    int nbase = n0 + wn * 64;
    int mbase = m0 + wm * 64;
    float xv[4][4];
#pragma unroll
    for (int ng = 0; ng < 4; ++ng)
#pragma unroll
        for (int r = 0; r < 4; ++r)
            xv[ng][r] = xx[b * NN + nbase + ng * 16 + g * 4 + r];
    float yv[4];
#pragma unroll
    for (int mg = 0; mg < 4; ++mg) yv[mg] = yy[b * MM + mbase + mg * 16 + q];

    // o = 2*acc - xx - yy, in-place, and store pd (dword, 64B-coalesced per 16-lane group)
#pragma unroll
    for (int ng = 0; ng < 4; ++ng)
#pragma unroll
        for (int r = 0; r < 4; ++r) {
            float* prow = pd + ((size_t)(b * NN + nbase + ng * 16 + g * 4 + r)) * MM + mbase + q;
#pragma unroll
            for (int mg = 0; mg < 4; ++mg) {
                float o = 2.f * acc[ng][mg][r] - xv[ng][r] - yv[mg];
                acc[ng][mg][r] = o;
                prow[mg * 16] = o;
            }
        }

    // row partials (max/sum over this wave's 64 m): fold mg in-register, shfl over q
#pragma unroll
    for (int ng = 0; ng < 4; ++ng)
#pragma unroll
        for (int r = 0; r < 4; ++r) {
            float mx = fmaxf(fmaxf(acc[ng][0][r], acc[ng][1][r]),
                             fmaxf(acc[ng][2][r], acc[ng][3][r]));
#pragma unroll
            for (int d = 1; d < 16; d <<= 1) mx = fmaxf(mx, __shfl_xor(mx, d));
            float s = __expf(acc[ng][0][r] - mx) + __expf(acc[ng][1][r] - mx) +
                      __expf(acc[ng][2][r] - mx) + __expf(acc[ng][3][r] - mx);
#pragma unroll
            for (int d = 1; d < 16; d <<= 1) s += __shfl_xor(s, d);
            if (q == 0) {
                int nl = wn * 64 + ng * 16 + g * 4 + r;
                rowm2[wm][nl] = mx;
                rows2[wm][nl] = s;
            }
        }

    // col partials (max/sum over this wave's 64 n): fold ng,r in-register, shfl over g
#pragma unroll
    for (int mg = 0; mg < 4; ++mg) {
        float cx = -3.4e38f;
#pragma unroll
        for (int ng = 0; ng < 4; ++ng)
#pragma unroll
            for (int r = 0; r < 4; ++r) cx = fmaxf(cx, acc[ng][mg][r]);
        cx = fmaxf(cx, __shfl_xor(cx, 16));
        cx = fmaxf(cx, __shfl_xor(cx, 32));
        float cs = 0.f;
#pragma unroll
        for (int ng = 0; ng < 4; ++ng)
#pragma unroll
            for (int r = 0; r < 4; ++r) cs += __expf(acc[ng][mg][r] - cx);
        cs += __shfl_xor(cs, 16);
        cs += __shfl_xor(cs, 32);
        if (lane < 16) {
            int ml = wm * 64 + mg * 16 + q;
            colm2[wn][ml] = cx;
            cols2[wn][ml] = cs;
        }
    }
    __syncthreads();

    if (t < 128) {
        float ma = rowm2[0][t], mb = rowm2[1][t];
        float M = fmaxf(ma, mb);
        float S = rows2[0][t] * __expf(ma - M) + rows2[1][t] * __expf(mb - M);
        size_t base = ((size_t)(b * MT2 + mt)) * NN + n0 + t;
        rpM[base] = M;
        rpS[base] = S;
    } else {
        int m = t - 128;
        float ma = colm2[0][m], mb = colm2[1][m];
        float M = fmaxf(ma, mb);
        float S = cols2[0][m] * __expf(ma - M) + cols2[1][m] * __expf(mb - M);
        size_t base = ((size_t)(b * NT2 + nt)) * MM + m0 + m;
        cpM[base] = M;
        cpS[base] = S;
    }
}

// ---------- K2: combine row/col partials (online softmax merge). z=0 rows, z=1 cols ----------
__global__ __launch_bounds__(256) void comb_rc_k(const float* __restrict__ rpM,
                                                 const float* __restrict__ rpS,
                                                 const float* __restrict__ cpM,
                                                 const float* __restrict__ cpS,
                                                 float* __restrict__ rowmax,
                                                 float* __restrict__ rowsum,
                                                 float* __restrict__ colmax,
                                                 float* __restrict__ colsum) {
    int b = blockIdx.y, which = blockIdx.z;
    int i = blockIdx.x * 256 + threadIdx.x;
    const float* pM = which ? cpM : rpM;
    const float* pS = which ? cpS : rpS;
    float* oM = which ? colmax : rowmax;
    float* oS = which ? colsum : rowsum;
    float Mv = -3.4e38f;
#pragma unroll
    for (int k = 0; k < 16; ++k) Mv = fmaxf(Mv, pM[(size_t)(b * 16 + k) * 2048 + i]);
    float S = 0.f;
#pragma unroll
    for (int k = 0; k < 16; ++k) {
        size_t o = (size_t)(b * 16 + k) * 2048 + i;
        S += pS[o] * __expf(pM[o] - Mv);
    }
    oM[b * 2048 + i] = Mv;
    oS[b * 2048 + i] = S;
}

// ---------- K3: fused cross pass — sRow partials AND sCol partials, single pd read ----------
__global__ __launch_bounds__(256) void cross_k(const float* __restrict__ pd,
                                               const float* __restrict__ rowmax,
                                               const float* __restrict__ rowsum,
                                               const float* __restrict__ colmax,
                                               const float* __restrict__ colsum,
                                               float* __restrict__ sRowp,   // [B,MT,N]
                                               float* __restrict__ sColp) { // [B,NCH,M]
    __shared__ float rmx[128], rin[128];
    __shared__ float rowpart[128][65];  // pad 65: conflict-free scalar access
    __shared__ float colacc[4][64];
    int b = blockIdx.z, nc = blockIdx.y, mtile = blockIdx.x;
    int m0 = mtile << 6;
    int t = threadIdx.x, mL = t & 63, ng = t >> 6;
    if (t < 128) {
        int n = nc * 128 + t;
        rmx[t] = rowmax[b * NN + n];
        rin[t] = 1.f / rowsum[b * NN + n];
    }
    float cmv = colmax[b * MM + m0 + mL];
    float civ = 1.f / colsum[b * MM + m0 + mL];
    __syncthreads();
    const float* base = pd + ((size_t)(b * NN + nc * 128)) * MM + m0 + mL;
    float scp = 0.f;
#pragma unroll
    for (int i = 0; i < 32; ++i) {
        int nl = (i << 2) + ng;
        float v = base[(size_t)nl * MM];
        scp += __expf(v - rmx[nl]) * rin[nl];
        rowpart[nl][mL] = __expf(v - cmv) * civ;
    }
    colacc[ng][mL] = scp;
    __syncthreads();
    if (t < 128) {
        float s = 0.f;
#pragma unroll
        for (int c = 0; c < 64; ++c) s += rowpart[t][c];
        sRowp[((size_t)(b * MT + mtile)) * NN + nc * 128 + t] = s;
    } else if (t < 192) {
        int m = t - 128;
        sColp[((size_t)(b * NCH + nc)) * MM + m0 + m] =
            colacc[0][m] + colacc[1][m] + colacc[2][m] + colacc[3][m];
    }
}

// ---------- K4: combine cross partials. z=0: sRow (32 tiles), z=1: sCol (16 chunks) ----------
__global__ __launch_bounds__(256) void comb_s_k(const float* __restrict__ sRowp,
                                                const float* __restrict__ sColp,
                                                float* __restrict__ sRow,
                                                float* __restrict__ sCol) {
    int b = blockIdx.y, which = blockIdx.z;
    int i = blockIdx.x * 256 + threadIdx.x;
    if (!which) {
        float s = 0.f;
#pragma unroll
        for (int k = 0; k < MT; ++k) s += sRowp[(size_t)(b * MT + k) * NN + i];
        sRow[b * NN + i] = s;
    } else {
        float s = 0.f;
#pragma unroll
        for (int k = 0; k < NCH; ++k) s += sColp[(size_t)(b * NCH + k) * MM + i];
        sCol[b * MM + i] = s;
    }
}

// ---------- K5: 614-th smallest via binary search on float bits (values >= 0) ----------
__global__ __launch_bounds__(64) void select_k(const float* __restrict__ sRow,
                                               const float* __restrict__ sCol,
                                               float* __restrict__ rth,
                                               float* __restrict__ cth) {
    int kind = blockIdx.x, b = blockIdx.y, t = threadIdx.x;
    const float* vals = (kind == 0) ? (sRow + b * NN) : (sCol + b * MM);
    float v[32];
#pragma unroll
    for (int i = 0; i < 32; ++i) v[i] = vals[t + (i << 6)];
    unsigned lo = 0u, hi = 0x7F800000u;
    while (lo < hi) {
        unsigned mid = lo + ((hi - lo) >> 1);
        float pv = __uint_as_float(mid);
        int c = 0;
#pragma unroll
        for (int i = 0; i < 32; ++i) c += (v[i] <= pv) ? 1 : 0;
#pragma unroll
        for (int off = 32; off > 0; off >>= 1) c += __shfl_down(c, off);
        c = __shfl(c, 0);
        if (c >= KSEL + 1) hi = mid; else lo = mid + 1;
    }
    if (t == 0) { if (kind == 0) rth[b] = __uint_as_float(lo); else cth[b] = __uint_as_float(lo); }
}

// ---------- K6: masks + src_weight ----------
__global__ __launch_bounds__(256) void masks_k(const float* __restrict__ sRow,
                                               const float* __restrict__ sCol,
                                               const float* __restrict__ rth,
                                               const float* __restrict__ cth,
                                               float* __restrict__ out) {
    int b = blockIdx.x, t = threadIdx.x;
    float r = rth[b], c = cth[b];
    int cnt = 0;
    bool ms[8];
#pragma unroll
    for (int i = 0; i < 8; ++i) {
        int n = t + (i << 8);
        ms[i] = sRow[b * NN + n] < r;
        out[OUT_MS + b * NN + n] = ms[i] ? 1.f : 0.f;
        out[OUT_MT + b * MM + n] = (sCol[b * MM + n] < c) ? 1.f : 0.f;
        cnt += ms[i] ? 0 : 1;
    }
#pragma unroll
    for (int off = 32; off > 0; off >>= 1) cnt += __shfl_down(cnt, off);
    __shared__ int wcnt[4];
    int wave = t >> 6, lane = t & 63;
    if (lane == 0) wcnt[wave] = cnt;
    __syncthreads();
    float inv = 1.f / (float)(wcnt[0] + wcnt[1] + wcnt[2] + wcnt[3]);
#pragma unroll
    for (int i = 0; i < 8; ++i) {
        int n = t + (i << 8);
        out[OUT_W + b * NN + n] = ms[i] ? 0.f : inv;
    }
}

// ---------- K7: src_corr = tgt @ w_sparse^T / colsum. Wave-per-row, 4 rows/block ----------
__global__ __launch_bounds__(256) void corr_k(const float* __restrict__ pd,
                                              const float* __restrict__ rowmax,
                                              const float* __restrict__ rowsum,
                                              const float* __restrict__ sRow,
                                              const float* __restrict__ sCol,
                                              const float* __restrict__ rth,
                                              const float* __restrict__ cth,
                                              const float* __restrict__ tgt,
                                              float* __restrict__ out) {
    int b = blockIdx.y;
    int n = (blockIdx.x << 2) + (threadIdx.x >> 6);
    int lane = threadIdx.x & 63;
    const float4* row4 = (const float4*)(pd + ((size_t)b * NN + n) * MM);
    const float4* sc4 = (const float4*)(sCol + b * MM);
    const float4* tg4 = (const float4*)(tgt + (size_t)b * 3 * MM);
    float rmax = rowmax[b * NN + n];
    float rsum = rowsum[b * NN + n];
    float cthv = cth[b];
    bool msrc = sRow[b * NN + n] < rth[b];
    float cs = 0.f, d0 = 0.f, d1 = 0.f, d2 = 0.f;
#pragma unroll
    for (int g = 0; g < 8; ++g) {
        int j = lane + (g << 6);
        float p[4], sc[4], t0[4], t1[4], t2[4];
        *(float4*)p = row4[j];
        *(float4*)sc = sc4[j];
        *(float4*)t0 = tg4[j];
        *(float4*)t1 = tg4[j + MM / 4];
        *(float4*)t2 = tg4[j + MM / 2];
#pragma unroll
        for (int c = 0; c < 4; ++c) {
            bool keep = msrc || (sc[c] < cthv) || (p[c] == rmax);
            if (keep) {
                float s = __expf(p[c] - rmax) / rsum;
                cs += s;
                d0 += s * t0[c];
                d1 += s * t1[c];
                d2 += s * t2[c];
            }
        }
    }
#pragma unroll
    for (int off = 32; off > 0; off >>= 1) {
        cs += __shfl_down(cs, off);
        d0 += __shfl_down(d0, off);
        d1 += __shfl_down(d1, off);
        d2 += __shfl_down(d2, off);
    }
    if (lane == 0) {
        cs = (cs < 1e-5f) ? 1e-5f : cs;
        out[(b * 3 + 0) * NN + n] = d0 / cs;
        out[(b * 3 + 1) * NN + n] = d1 / cs;
        out[(b * 3 + 2) * NN + n] = d2 / cs;
    }
}

extern "C" void kernel_launch(void* const* d_in, const int* in_sizes, int n_in,
                              void* d_out, int out_size, void* d_ws, size_t ws_size,
                              hipStream_t stream) {
    const float* src_emb = (const float*)d_in[0];   // [B,C,N]
    const float* tgt_emb = (const float*)d_in[1];   // [B,C,M]
    // d_in[2] = src, unused by the reference
    const float* tgt = (const float*)d_in[3];       // [B,3,M]
    float* out = (float*)d_out;

    float* ws = (float*)d_ws;
    float* pd     = ws;                               // B*N*M
    float* xx     = pd + (size_t)BB * NN * MM;        // B*N
    float* yy     = xx + BB * NN;                     // B*M
    float* rowmax = yy + BB * MM;                     // B*N
    float* rowsum = rowmax + BB * NN;                 // B*N
    float* colmax = rowsum + BB * NN;                 // B*M
    float* colsum = colmax + BB * MM;                 // B*M
    float* sRow   = colsum + BB * MM;                 // B*N
    float* sCol   = sRow + BB * NN;                   // B*M
    float* rth    = sCol + BB * MM;                   // B
    float* cth    = rth + BB;                         // B
    float* rpM    = cth + BB;                         // B*16*N
    float* rpS    = rpM + (size_t)BB * 16 * NN;       // B*16*N
    float* cpM    = rpS + (size_t)BB * 16 * NN;       // B*16*M
    float* cpS    = cpM + (size_t)BB * 16 * MM;       // B*16*M
    float* sRowp  = cpS + (size_t)BB * 16 * MM;       // B*MT*N
    float* sColp  = sRowp + (size_t)BB * MT * NN;     // B*NCH*M
    unsigned* At0 = (unsigned*)(sColp + (size_t)BB * NCH * MM);  // each B*N*32 u32
    unsigned* At1 = At0 + (size_t)BB * NN * 32;
    unsigned* At2 = At1 + (size_t)BB * NN * 32;
    unsigned* Bt0 = At2 + (size_t)BB * NN * 32;
    unsigned* Bt1 = Bt0 + (size_t)BB * MM * 32;
    unsigned* Bt2 = Bt1 + (size_t)BB * MM * 32;

    split_k<<<dim3(NN / 64, BB), 256, 0, stream>>>(src_emb, xx, At0, At1, At2);
    split_k<<<dim3(MM / 64, BB), 256, 0, stream>>>(tgt_emb, yy, Bt0, Bt1, Bt2);
    gemm_pd_k<<<dim3(16, 16, BB), 256, 0, stream>>>(At0, At1, At2, Bt0, Bt1, Bt2,
                                                    xx, yy, pd, rpM, rpS, cpM, cpS);
    comb_rc_k<<<dim3(2048 / 256, BB, 2), 256, 0, stream>>>(rpM, rpS, cpM, cpS,
                                                           rowmax, rowsum, colmax, colsum);
    cross_k<<<dim3(MT, NCH, BB), 256, 0, stream>>>(pd, rowmax, rowsum, colmax, colsum, sRowp, sColp);
    comb_s_k<<<dim3(2048 / 256, BB, 2), 256, 0, stream>>>(sRowp, sColp, sRow, sCol);
    select_k<<<dim3(2, BB), 64, 0, stream>>>(sRow, sCol, rth, cth);
    masks_k<<<dim3(BB), 256, 0, stream>>>(sRow, sCol, rth, cth, out);
    corr_k<<<dim3(NN / 4, BB), 256, 0, stream>>>(pd, rowmax, rowsum, sRow, sCol, rth, cth, tgt, out);
}